// Round 5
// baseline (646.720 us; speedup 1.0000x reference)
//
#include <hip/hip_runtime.h>

// Problem constants (match reference setup_inputs)
constexpr int N_NODES = 50000;
constexpr int N_EDGES = 25000;
constexpr int C = 256;   // IN == OUT == 256 channels
constexpr int L = 32;    // incidence list width

// Transposed bf16 weights in device globals.
__device__ ushort W1T_g[C * C];   // [n][k] bf16
__device__ ushort W2T_g[C * C];   // [n][k] bf16

__device__ __forceinline__ ushort f2bf(float f) {
    union { float f; unsigned int u; } c; c.f = f;
    unsigned int r = c.u + 0x7FFFu + ((c.u >> 16) & 1u);   // RNE
    return (ushort)(r >> 16);
}
__device__ __forceinline__ float bflo(unsigned int u) {
    union { unsigned int x; float f; } c; c.x = u << 16; return c.f;
}
__device__ __forceinline__ float bfhi(unsigned int u) {
    union { unsigned int x; float f; } c; c.x = u & 0xFFFF0000u; return c.f;
}
__device__ __forceinline__ void acc_uint4(float* acc, const uint4 v) {
    acc[0] += bflo(v.x); acc[1] += bfhi(v.x);
    acc[2] += bflo(v.y); acc[3] += bfhi(v.y);
    acc[4] += bflo(v.z); acc[5] += bfhi(v.z);
    acc[6] += bflo(v.w); acc[7] += bfhi(v.w);
}

// ---------------------------------------------------------------------------
// x [N,256] fp32 -> xb bf16. 4 elems/thread.
// ---------------------------------------------------------------------------
__global__ __launch_bounds__(256) void convert_x_kernel(
    const float* __restrict__ x, ushort* __restrict__ xb)
{
    const size_t i = ((size_t)blockIdx.x * 256 + threadIdx.x) * 4;
    const float4 v = *reinterpret_cast<const float4*>(x + i);
    ushort4 o;
    o.x = f2bf(v.x); o.y = f2bf(v.y); o.z = f2bf(v.z); o.w = f2bf(v.w);
    *reinterpret_cast<ushort4*>(xb + i) = o;
}

// ---------------------------------------------------------------------------
// Zero the redirect rows: xb[N_NODES,:] and edge[N_EDGES,:].
// Must run every launch (ws re-poisoned to 0xAA).
// ---------------------------------------------------------------------------
__global__ __launch_bounds__(64) void zrow_kernel(
    ushort* __restrict__ xb_zrow, ushort* __restrict__ edge_zrow)
{
    const int t = threadIdx.x;
    const uint4 z = {0u, 0u, 0u, 0u};
    if (t < 32) reinterpret_cast<uint4*>(xb_zrow)[t] = z;
    else        reinterpret_cast<uint4*>(edge_zrow)[t - 32] = z;
}

// ---------------------------------------------------------------------------
// W [256k,256n] fp32 row-major -> WT [n][k] bf16 (transposed), via LDS tile.
// ---------------------------------------------------------------------------
__global__ __launch_bounds__(256) void wconv_kernel(
    const float* __restrict__ W1, const float* __restrict__ W2)
{
    const float* W  = blockIdx.z ? W2 : W1;
    ushort* WT      = blockIdx.z ? W2T_g : W1T_g;
    __shared__ float t[64][65];
    const int rr = threadIdx.x >> 6;    // 0..3
    const int cc = threadIdx.x & 63;    // 0..63
    const int br = blockIdx.x * 64;     // k tile
    const int bc = blockIdx.y * 64;     // n tile
#pragma unroll
    for (int i = 0; i < 16; ++i) {
        const int row = i * 4 + rr;
        t[row][cc] = W[(size_t)(br + row) * C + bc + cc];
    }
    __syncthreads();
#pragma unroll
    for (int i = 0; i < 16; ++i) {
        const int n = i * 4 + rr;
        WT[(size_t)(bc + n) * C + br + cc] = f2bf(t[cc][n]);
    }
}

// ---------------------------------------------------------------------------
// Chunked gather-average with zero-row redirect.
//   dst[row, chunk*64 .. +64] = (1/cnt) * sum_l src[sidx[row,l], ...]
// - 4 channel-chunks x 64 ch: chunk = bid&3; with bid%8->XCD round-robin each
//   XCD sees a fixed table slice (R4 measured FETCH == compulsory for this).
// - invalid ids (<=0) redirected to `zrow` (a zeroed table row) during LDS
//   staging -> hot loop is pure load+accumulate, no correction registers.
// - cnt==0 => reference gives uniform avg of row 0 == row 0 (never taken on
//   random data; kept for safety).
// - __launch_bounds__(256,6): R4's VGPR=96 build sat at 20% occupancy and
//   was latency-bound; cap regs to recover waves.
// ---------------------------------------------------------------------------
__global__ __launch_bounds__(256, 6) void gather_chunk_kernel(
    const ushort* __restrict__ src, const int* __restrict__ idx,
    ushort* __restrict__ dst, int nrows, int zrow)
{
    constexpr int CH = 64, NCHUNK = 4;
    constexpr int LPR = CH / 8;        // 8 lanes per row
    constexpr int RPB = 256 / LPR;     // 32 rows per block
    const int chunk = blockIdx.x & (NCHUNK - 1);
    const int rb    = (int)(blockIdx.x / NCHUNK) * RPB;
    const int t     = threadIdx.x;

    __shared__ int sidx[RPB][33];
#pragma unroll
    for (int i = 0; i < (RPB * L) / 256; ++i) {
        const int flat = i * 256 + t;
        const int r = flat >> 5, l = flat & 31;
        int raw = (rb + r < nrows) ? idx[(size_t)(rb + r) * L + l] : 0;
        sidx[r][l] = (raw > 0) ? raw : zrow;
    }
    __syncthreads();

    const int r   = t / LPR;
    const int ch  = chunk * CH + (t % LPR) * 8;
    const int row = rb + r;

    float acc[8] = {0.f, 0.f, 0.f, 0.f, 0.f, 0.f, 0.f, 0.f};
    int cnt = 0;
#pragma unroll
    for (int l = 0; l < L; ++l) {
        const int id = sidx[r][l];
        cnt += (id != zrow) ? 1 : 0;
        const uint4 v = *reinterpret_cast<const uint4*>(
            src + (size_t)id * C + ch);
        acc_uint4(acc, v);
    }
    if (row >= nrows) return;

    float inv;
    if (cnt == 0) {            // all-padding row: uniform avg == table row 0
        const uint4 v = *reinterpret_cast<const uint4*>(src + ch);
        acc[0] = bflo(v.x); acc[1] = bfhi(v.x); acc[2] = bflo(v.y); acc[3] = bfhi(v.y);
        acc[4] = bflo(v.z); acc[5] = bfhi(v.z); acc[6] = bflo(v.w); acc[7] = bfhi(v.w);
        inv = 1.f;
    } else {
        inv = 1.f / (float)cnt;
    }

    uint4 o;
    o.x = (unsigned)f2bf(acc[0] * inv) | ((unsigned)f2bf(acc[1] * inv) << 16);
    o.y = (unsigned)f2bf(acc[2] * inv) | ((unsigned)f2bf(acc[3] * inv) << 16);
    o.z = (unsigned)f2bf(acc[4] * inv) | ((unsigned)f2bf(acc[5] * inv) << 16);
    o.w = (unsigned)f2bf(acc[6] * inv) | ((unsigned)f2bf(acc[7] * inv) << 16);
    *reinterpret_cast<uint4*>(dst + (size_t)row * C + ch) = o;
}

// ---------------------------------------------------------------------------
// MFMA bf16 GEMM: C[M,256] = A[M,256] @ W, W transposed bf16 [n][k].
// Wave tile: 32 rows x 128 cols. grid (ceil(M/128), 2).
// C/D: col=lane&15, row=quad*4+reg (m89-verified layout).
// F32OUT: write fp32 (final output), else bf16.
// ---------------------------------------------------------------------------
typedef __attribute__((ext_vector_type(8))) short bf16x8;
typedef __attribute__((ext_vector_type(4))) float f32x4;

template <bool RELU, bool F32OUT>
__global__ __launch_bounds__(256) void gemm_mfma_kernel(
    const ushort* __restrict__ A, int which_w, void* __restrict__ Cmat, int M)
{
    const ushort* __restrict__ BT = which_w ? W2T_g : W1T_g;
    const int wave  = threadIdx.x >> 6;
    const int lane  = threadIdx.x & 63;
    const int quad  = lane >> 4;
    const int l16   = lane & 15;
    const int base  = (blockIdx.x * 4 + wave) * 32;
    const int nbase = blockIdx.y * 128;

    int m0 = base + l16;      if (m0 > M - 1) m0 = M - 1;
    int m1 = base + 16 + l16; if (m1 > M - 1) m1 = M - 1;

    f32x4 acc[2][8];
    const f32x4 zero = {0.f, 0.f, 0.f, 0.f};
#pragma unroll
    for (int p = 0; p < 2; ++p)
#pragma unroll
        for (int t = 0; t < 8; ++t) acc[p][t] = zero;

    const ushort* a0 = A + (size_t)m0 * C + quad * 8;
    const ushort* a1 = A + (size_t)m1 * C + quad * 8;
    const ushort* br = BT + (size_t)(nbase + l16) * C + quad * 8;

#pragma unroll
    for (int k0 = 0; k0 < C; k0 += 32) {
        const bf16x8 av0 = *reinterpret_cast<const bf16x8*>(a0 + k0);
        const bf16x8 av1 = *reinterpret_cast<const bf16x8*>(a1 + k0);
#pragma unroll
        for (int t = 0; t < 8; ++t) {
            const bf16x8 b = *reinterpret_cast<const bf16x8*>(
                br + (size_t)t * 16 * C + k0);
            acc[0][t] = __builtin_amdgcn_mfma_f32_16x16x32_bf16(av0, b, acc[0][t], 0, 0, 0);
            acc[1][t] = __builtin_amdgcn_mfma_f32_16x16x32_bf16(av1, b, acc[1][t], 0, 0, 0);
        }
    }

#pragma unroll
    for (int p = 0; p < 2; ++p)
#pragma unroll
    for (int t = 0; t < 8; ++t)
#pragma unroll
    for (int r = 0; r < 4; ++r) {
        const int gm = base + p * 16 + quad * 4 + r;
        if (gm < M) {
            float v = acc[p][t][r];
            if (RELU) v = fmaxf(v, 0.f);
            if (F32OUT)
                ((float*)Cmat)[(size_t)gm * C + nbase + t * 16 + l16] = v;
            else
                ((ushort*)Cmat)[(size_t)gm * C + nbase + t * 16 + l16] = f2bf(v);
        }
    }
}

// ---------------------------------------------------------------------------
// Pipeline (BOTH gathers hoisted next to their cheap side -- linearity):
//   xb   = bf16(x)                 [N+1,256] bf16 (row N zeroed: redirect)
//   tmp1 = gather(xb, seq)         [E,256]   bf16
//   edge = relu(tmp1 @ W1)         [E+1,256] bf16 (row E zeroed: redirect)
//   agg  = gather(edge, useq)      [N,256]   bf16 (reuses xb region)
//   out  = agg @ W2                [N,256]   fp32 -> d_out
// ws: (N+1)C + E*C + (E+1)C bf16 = 51.2 MB + 1 KB
// ---------------------------------------------------------------------------
extern "C" void kernel_launch(void* const* d_in, const int* in_sizes, int n_in,
                              void* d_out, int out_size, void* d_ws, size_t ws_size,
                              hipStream_t stream) {
    const float* x    = (const float*)d_in[0];
    const int*   seq  = (const int*)d_in[1];
    const int*   useq = (const int*)d_in[2];
    const float* W1   = (const float*)d_in[3];
    const float* W2   = (const float*)d_in[4];
    float* out = (float*)d_out;

    ushort* xb   = (ushort*)d_ws;                        // (N+1) x C
    ushort* tmp1 = xb + (size_t)(N_NODES + 1) * C;       // E x C
    ushort* edge = tmp1 + (size_t)N_EDGES * C;           // (E+1) x C
    ushort* agg  = xb;                                   // N x C (xb dead then)

    convert_x_kernel<<<dim3((N_NODES * C) / (256 * 4)), dim3(256), 0, stream>>>(x, xb);
    zrow_kernel<<<dim3(1), dim3(64), 0, stream>>>(
        xb + (size_t)N_NODES * C, edge + (size_t)N_EDGES * C);
    wconv_kernel<<<dim3(4, 4, 2), dim3(256), 0, stream>>>(W1, W2);

    // gather1: table xb (zrow = N_NODES)
    gather_chunk_kernel<<<dim3(4 * ((N_EDGES + 31) / 32)), dim3(256), 0, stream>>>(
        xb, seq, tmp1, N_EDGES, N_NODES);

    gemm_mfma_kernel<true, false><<<dim3((N_EDGES + 127) / 128, 2), dim3(256), 0, stream>>>(
        tmp1, 0, edge, N_EDGES);

    // gather2: table edge (zrow = N_EDGES)
    gather_chunk_kernel<<<dim3(4 * ((N_NODES + 31) / 32)), dim3(256), 0, stream>>>(
        edge, useq, agg, N_NODES, N_EDGES);

    gemm_mfma_kernel<false, true><<<dim3((N_NODES + 127) / 128, 2), dim3(256), 0, stream>>>(
        agg, 1, out, N_NODES);
}